// Round 5
// baseline (543.659 us; speedup 1.0000x reference)
//
#include <hip/hip_runtime.h>

// MinkowskiBroadcast: out[p][c] = x_glob[batch_idx[p]][c]
//   x_glob:    [32][128] f32  (16 KB -> L1/L2 resident)
//   batch_idx: [1'000'000] i32 (4 MB, read once)
//   out:       [1'000'000][128] f32  (512 MB, write-BW bound)
//
// Decompose into 16B chunks: 32 chunks per point-row. Chunk g:
//   p = g >> 5 (point), c4 = g & 31 (channel quad).
// Lanes 0..31 of each 32-lane group share p (uniform batch_idx load ->
// one cache line per wave); consecutive lanes write consecutive 16 B
// -> 1 KB fully-coalesced store per wave instruction.
//
// Roofline: 516 MB total traffic / 6.3 TB/s achievable ~= 82 us floor.
//
// NOTE: __builtin_nontemporal_* requires a NATIVE clang vector type —
// HIP's float4 (HIP_vector_type class) does not compile (r4 failure).

typedef float v4f __attribute__((ext_vector_type(4)));

__global__ __launch_bounds__(256) void
minkowski_broadcast_kernel(const v4f* __restrict__ xg,   // [32*32] 16B quads
                           const int* __restrict__ bidx, // [N]
                           v4f*       __restrict__ out,  // [N*32]
                           int n_chunks) {
    int stride = (int)(gridDim.x * blockDim.x);
    for (int g = (int)(blockIdx.x * blockDim.x + threadIdx.x);
         g < n_chunks; g += stride) {
        int p  = g >> 5;
        int c4 = g & 31;
        // batch_idx streamed exactly once -> nontemporal (don't pollute L2);
        // uniform across the 32-lane group -> single cacheline request.
        int b  = __builtin_nontemporal_load(&bidx[p]);
        v4f v  = xg[(b << 5) + c4];   // cached: 16 KB table, L1-resident
        // Output streamed exactly once, 16x aggregate L2 -> nt store.
        __builtin_nontemporal_store(v, &out[g]);
    }
}

extern "C" void kernel_launch(void* const* d_in, const int* in_sizes, int n_in,
                              void* d_out, int out_size, void* d_ws, size_t ws_size,
                              hipStream_t stream) {
    const v4f* xg   = (const v4f*)d_in[0];  // x_glob [32][128] f32
    const int* bidx = (const int*)d_in[1];  // batch_idx [N] i32
    v4f*       out  = (v4f*)d_out;          // [N][128] f32

    const int n_chunks = out_size / 4;      // 16B chunks (N * 128 / 4)

    // Memory-bound: cap grid at ~2048 blocks, grid-stride the rest (G11).
    const int block = 256;
    const int grid  = 2048;
    minkowski_broadcast_kernel<<<grid, block, 0, stream>>>(xg, bidx, out, n_chunks);
}

// Round 7
// 536.612 us; speedup vs baseline: 1.0131x; 1.0131x over previous
//
#include <hip/hip_runtime.h>

// MinkowskiBroadcast: out[p][c] = x_glob[batch_idx[p]][c]
//   x_glob:    [32][128] f32  (16 KB -> L1/L2 resident)
//   batch_idx: [1'000'000] i32 (4 MB, read once)
//   out:       [1'000'000][128] f32  (512 MB, write-BW bound)
//
// Decompose into 16B chunks: 32 chunks per point-row. Chunk g:
//   p = g >> 5 (point), c4 = g & 31 (channel quad).
// Lanes 0..31 of each 32-lane group share p (uniform batch_idx load ->
// one cache line per group); consecutive lanes write consecutive 16 B
// -> 1 KB fully-coalesced store per wave instruction.
//
// Roofline: 516 MB total traffic / 6.3 TB/s achievable ~= 82 us floor.
// Evidence the floor is real: harness fillBuffer dispatches sustain
// 6.28-6.36 TB/s on this same output buffer with PLAIN stores.
//
// R5 post-mortem: nt-store/nt-load version measured 543 us (0.95 TB/s).
// The only delta vs the 6.3 TB/s fill kernels was the `nt` cache-bypass
// policy -> removed all nontemporal hints (A/B of cache policy).

typedef float v4f __attribute__((ext_vector_type(4)));

__global__ __launch_bounds__(256) void
minkowski_broadcast_kernel(const v4f* __restrict__ xg,   // [32*32] 16B quads
                           const int* __restrict__ bidx, // [N]
                           v4f*       __restrict__ out,  // [N*32]
                           int n_chunks) {
    int stride = (int)(gridDim.x * blockDim.x);
    for (int g = (int)(blockIdx.x * blockDim.x + threadIdx.x);
         g < n_chunks; g += stride) {
        int p  = g >> 5;
        int c4 = g & 31;
        int b  = bidx[p];              // uniform per 32-lane group, L1 hit
        v4f v  = xg[(b << 5) + c4];    // 16 KB table, L1-resident
        out[g] = v;                    // plain cached store (fills prove 6.3 TB/s)
    }
}

extern "C" void kernel_launch(void* const* d_in, const int* in_sizes, int n_in,
                              void* d_out, int out_size, void* d_ws, size_t ws_size,
                              hipStream_t stream) {
    const v4f* xg   = (const v4f*)d_in[0];  // x_glob [32][128] f32
    const int* bidx = (const int*)d_in[1];  // batch_idx [N] i32
    v4f*       out  = (v4f*)d_out;          // [N][128] f32

    const int n_chunks = out_size / 4;      // 16B chunks (N * 128 / 4)

    // Memory-bound: cap grid at ~2048 blocks, grid-stride the rest (G11).
    const int block = 256;
    const int grid  = 2048;
    minkowski_broadcast_kernel<<<grid, block, 0, stream>>>(xg, bidx, out, n_chunks);
}

// Round 10
// 516.137 us; speedup vs baseline: 1.0533x; 1.0397x over previous
//
#include <hip/hip_runtime.h>

// MinkowskiBroadcast: out[p][c] = x_glob[batch_idx[p]][c]
//   x_glob:    [32][128] f32  (16 KB -> staged in LDS)
//   batch_idx: [1'000'000] i32 (4 MB, read once)
//   out:       [1'000'000][128] f32  (512 MB, write-BW bound)
//
// R7 post-mortem: nt-policy removal was neutral (543->536 us). New theory:
// vmcnt store-drain serialization. In the naive loop, iter i+1's index load
// is issued AFTER iter i's store on the same vmcnt queue; waiting for the
// load (oldest-first semantics) drains the store -> ~1 store per HBM store
// latency per wave -> ~1 TB/s. Fix:
//   (a) prefetch 8 iterations of bidx BEFORE issuing the batch's stores
//       (loads older than stores -> waits never drain stores),
//   (b) stage x_glob in LDS so gather reads use lgkmcnt, not vmcnt.
// Store pattern unchanged: 64 lanes x 16 B consecutive = 1 KB/wave,
// plain cached stores (harness fills prove 6.3 TB/s on this path).

typedef float v4f __attribute__((ext_vector_type(4)));

#define BATCH 8

__global__ __launch_bounds__(256) void
minkowski_broadcast_kernel(const v4f* __restrict__ xg,   // [32*32] 16B quads
                           const int* __restrict__ bidx, // [N]
                           v4f*       __restrict__ out,  // [N*32]
                           int n_chunks) {
    __shared__ v4f lds_xg[32 * 32];   // 16 KB: whole x_glob table
    for (int i = threadIdx.x; i < 32 * 32; i += 256)
        lds_xg[i] = xg[i];
    __syncthreads();

    const int tid    = (int)(blockIdx.x * blockDim.x + threadIdx.x);
    const int stride = (int)(gridDim.x * blockDim.x);   // 524288 (mult of 32:
                                                        // p uniform per group)
    // Prefetch indices for the first batch.
    int b[BATCH];
#pragma unroll
    for (int k = 0; k < BATCH; ++k) {
        int g = tid + k * stride;
        b[k] = (g < n_chunks) ? bidx[g >> 5] : 0;
    }

    for (int base = tid; base < n_chunks; base += BATCH * stride) {
        // (a) issue NEXT batch's index loads first -> older than the stores
        //     below, so their waitcnt never drains the store queue.
        int bn[BATCH];
        const int nbase = base + BATCH * stride;
#pragma unroll
        for (int k = 0; k < BATCH; ++k) {
            int g = nbase + k * stride;
            bn[k] = (g < n_chunks) ? bidx[g >> 5] : 0;
        }
        // (b) gather from LDS (lgkmcnt queue) and stream the stores.
#pragma unroll
        for (int k = 0; k < BATCH; ++k) {
            int g = base + k * stride;
            if (g < n_chunks)
                out[g] = lds_xg[(b[k] << 5) + (g & 31)];
        }
#pragma unroll
        for (int k = 0; k < BATCH; ++k) b[k] = bn[k];
    }
}

extern "C" void kernel_launch(void* const* d_in, const int* in_sizes, int n_in,
                              void* d_out, int out_size, void* d_ws, size_t ws_size,
                              hipStream_t stream) {
    const v4f* xg   = (const v4f*)d_in[0];  // x_glob [32][128] f32
    const int* bidx = (const int*)d_in[1];  // batch_idx [N] i32
    v4f*       out  = (v4f*)d_out;          // [N][128] f32

    const int n_chunks = out_size / 4;      // 16B chunks (N * 128 / 4)

    const int block = 256;
    const int grid  = 2048;
    minkowski_broadcast_kernel<<<grid, block, 0, stream>>>(xg, bidx, out, n_chunks);
}